// Round 10
// baseline (188.819 us; speedup 1.0000x reference)
//
#include <hip/hip_runtime.h>
#include <stdint.h>

#define NB 4
#define NT 2048
#define ND 512
#define NH 8
#define NDK 64
#define NM (NB*NT)   // 8192 rows

typedef __attribute__((ext_vector_type(8))) short short8;
typedef __attribute__((ext_vector_type(4))) short bs4;     // 4 bf16 (2 VGPR)
typedef __attribute__((ext_vector_type(4))) float f32x4;

// round-to-nearest-even fp32 -> bf16
__device__ __forceinline__ unsigned short f2b(float f) {
    union { float f; uint32_t u; } v; v.f = f;
    return (unsigned short)((v.u + 0x7FFFu + ((v.u >> 16) & 1u)) >> 16);
}

__device__ __forceinline__ void load_lds16(const void* g, void* l) {
    void* gn = const_cast<void*>(g);
    __builtin_amdgcn_global_load_lds((__attribute__((address_space(1))) void*)gn,
                                     (__attribute__((address_space(3))) void*)l,
                                     16, 0, 0);
}

// ---------------------------------------------------------------------------
// fp32 -> bf16 conversion of x + Wq,Wk,Wv,Wo, packed into ws.
// ---------------------------------------------------------------------------
__global__ void convert_all(const float* __restrict__ x,  const float* __restrict__ wq,
                            const float* __restrict__ wk, const float* __restrict__ wv,
                            const float* __restrict__ wo, unsigned short* __restrict__ dst) {
    size_t i = ((size_t)blockIdx.x * 256 + threadIdx.x) * 4;
    const float* src; size_t off;
    if (i < 4194304) { src = x; off = i; }
    else {
        size_t j = i - 4194304;
        src = (j < 262144) ? wq : (j < 524288) ? wk : (j < 786432) ? wv : wo;
        off = j & 262143;
    }
    f32x4 v = *(const f32x4*)(src + off);
    ushort4 r;
    r.x = f2b(v[0]); r.y = f2b(v[1]); r.z = f2b(v[2]); r.w = f2b(v[3]);
    *(ushort4*)(dst + i) = r;
}

// ---------------------------------------------------------------------------
// Projections. z=0: Q = x@Wq.T (scaled), z=1: K = x@Wk.T  -> row-major bf16.
// z=2: VT = Wv@x.T directly -> VT[(b*8+h)*64+d][t], coalesced along t.
// BK=64, XOR-swizzled chunks: LDS chunk (r,p) holds global chunk p^(r&7);
// DMA deposits contiguous (no write conflicts), reads 2-way (free).
// 8 K-iterations (half the barriers of BK=32).
// ---------------------------------------------------------------------------
__global__ __launch_bounds__(256, 3) void proj_gemm(
        const unsigned short* __restrict__ X,
        const unsigned short* __restrict__ Wbase,
        const float* __restrict__ bias0, const float* __restrict__ bias1,
        const float* __restrict__ bias2,
        unsigned short* __restrict__ Obase, unsigned short* __restrict__ VTb,
        float scale0) {
    const int z = blockIdx.z;
    const float* bias = (z == 0) ? bias0 : (z == 1 ? bias1 : bias2);
    const float scale = (z == 0) ? scale0 : 1.0f;

    int rowBase, colBase;
    const unsigned short *Ap, *Bp;
    if (z == 2) {   // A = Wv (rows=d), B = x (rows=t)
        rowBase = blockIdx.x * 128;  colBase = blockIdx.y * 128;
        Ap = Wbase + 2 * (ND * ND);  Bp = X;
    } else {        // A = x (rows=t), B = Wq/Wk (rows=d)
        rowBase = blockIdx.y * 128;  colBase = blockIdx.x * 128;
        Ap = X;                      Bp = Wbase + (size_t)z * (ND * ND);
    }

    __shared__ alignas(16) unsigned short ldsA[128 * 64];   // 16 KB
    __shared__ alignas(16) unsigned short ldsW[128 * 64];   // 16 KB

    const int tid = threadIdx.x;
    const int lane = tid & 63, wave = tid >> 6;
    const int quad = lane >> 4, l15 = lane & 15;
    const int wm = wave >> 1, wn = wave & 1;

    // staging: call c covers rows c*32 + (tid>>3); chunk g = (tid&7)^((tid>>3)&7)
    const int rS = tid >> 3;                      // 0..31
    const int gc = (tid & 7) ^ (rS & 7);          // call-invariant (c*32 ≡ 0 mod 8)
    const unsigned short* gA = Ap + (size_t)(rowBase + rS) * ND + gc * 8;
    const unsigned short* gW = Bp + (size_t)(colBase + rS) * ND + gc * 8;
    const int ldst = wave * 512;                  // + c*2048

    // read-side swizzle
    const int swz = l15 & 7;

    f32x4 acc[4][4];
#pragma unroll
    for (int i = 0; i < 4; i++)
#pragma unroll
        for (int j = 0; j < 4; j++) acc[i][j] = (f32x4)0.0f;

    for (int kt = 0; kt < ND / 64; ++kt) {
        __syncthreads();
#pragma unroll
        for (int c = 0; c < 4; ++c) {
            load_lds16(gA + (size_t)c * 32 * ND, ldsA + c * 2048 + ldst);
            load_lds16(gW + (size_t)c * 32 * ND, ldsW + c * 2048 + ldst);
        }
        gA += 64; gW += 64;
        __syncthreads();

#pragma unroll
        for (int ks = 0; ks < 2; ++ks) {
            short8 af[4], bfm[4];
#pragma unroll
            for (int mt = 0; mt < 4; ++mt)
                af[mt] = *(const short8*)(ldsA + (wm * 64 + mt * 16 + l15) * 64
                                          + (((ks * 4 + quad) ^ swz) * 8));
#pragma unroll
            for (int nt = 0; nt < 4; ++nt)
                bfm[nt] = *(const short8*)(ldsW + (wn * 64 + nt * 16 + l15) * 64
                                           + (((ks * 4 + quad) ^ swz) * 8));
#pragma unroll
            for (int mt = 0; mt < 4; ++mt)
#pragma unroll
                for (int nt = 0; nt < 4; ++nt)
                    acc[mt][nt] = __builtin_amdgcn_mfma_f32_16x16x32_bf16(
                        af[mt], bfm[nt], acc[mt][nt], 0, 0, 0);
        }
    }

    if (z == 2) {
        const int bz = colBase >> 11;
        const int t0 = colBase & 2047;
        unsigned short* VTo = VTb + ((size_t)(bz * 512 + rowBase)) * NT + t0;
#pragma unroll
        for (int mt = 0; mt < 4; mt++)
#pragma unroll
            for (int reg = 0; reg < 4; reg++) {
                int m = wm * 64 + mt * 16 + quad * 4 + reg;
                float bm = bias[rowBase + m];
                unsigned short* dst = VTo + (size_t)m * NT + wn * 64 + l15;
#pragma unroll
                for (int nt = 0; nt < 4; nt++)
                    dst[nt * 16] = f2b(acc[mt][nt][reg] + bm);
            }
    } else {
        float biasr[4];
#pragma unroll
        for (int nt = 0; nt < 4; nt++)
            biasr[nt] = bias[colBase + wn * 64 + nt * 16 + l15];
        unsigned short* Oz = Obase + (size_t)z * ((size_t)NM * ND);
#pragma unroll
        for (int mt = 0; mt < 4; mt++) {
            int row = rowBase + wm * 64 + mt * 16 + quad * 4;
#pragma unroll
            for (int reg = 0; reg < 4; reg++) {
                unsigned short* dst = Oz + (size_t)(row + reg) * ND + colBase + wn * 64 + l15;
#pragma unroll
                for (int nt = 0; nt < 4; nt++)
                    dst[nt * 16] = f2b((acc[mt][nt][reg] + biasr[nt]) * scale);
            }
        }
    }
}

// ---------------------------------------------------------------------------
// Output projection (fp32 out): 64x128 tile, 2x2 wave grid, BK=64 + swizzle.
// grid (4, 128) = 512 blocks.
// ---------------------------------------------------------------------------
__global__ __launch_bounds__(256, 4) void out_gemm(
        const unsigned short* __restrict__ A, const unsigned short* __restrict__ W,
        const float* __restrict__ bias, float* __restrict__ OF) {
    __shared__ alignas(16) unsigned short ldsA[64 * 64];    // 8 KB
    __shared__ alignas(16) unsigned short ldsW[128 * 64];   // 16 KB

    const int tid = threadIdx.x;
    const int lane = tid & 63, wave = tid >> 6;
    const int quad = lane >> 4, l15 = lane & 15;
    const int wm = wave >> 1, wn = wave & 1;
    const int rowBase = blockIdx.y * 64;
    const int colBase = blockIdx.x * 128;

    const int rS = tid >> 3;
    const int gc = (tid & 7) ^ (rS & 7);
    const unsigned short* gA = A + (size_t)(rowBase + rS) * ND + gc * 8;
    const unsigned short* gW = W + (size_t)(colBase + rS) * ND + gc * 8;
    const int ldst = wave * 512;
    const int swz = l15 & 7;

    f32x4 acc[2][4];
#pragma unroll
    for (int mt = 0; mt < 2; mt++)
#pragma unroll
        for (int nt = 0; nt < 4; nt++) acc[mt][nt] = (f32x4)0.0f;

    for (int kt = 0; kt < ND / 64; ++kt) {
        __syncthreads();
#pragma unroll
        for (int c = 0; c < 2; ++c)
            load_lds16(gA + (size_t)c * 32 * ND, ldsA + c * 2048 + ldst);
#pragma unroll
        for (int c = 0; c < 4; ++c)
            load_lds16(gW + (size_t)c * 32 * ND, ldsW + c * 2048 + ldst);
        gA += 64; gW += 64;
        __syncthreads();

#pragma unroll
        for (int ks = 0; ks < 2; ++ks) {
            short8 af[2], bfm[4];
#pragma unroll
            for (int mt = 0; mt < 2; ++mt)
                af[mt] = *(const short8*)(ldsA + (wm * 32 + mt * 16 + l15) * 64
                                          + (((ks * 4 + quad) ^ swz) * 8));
#pragma unroll
            for (int nt = 0; nt < 4; ++nt)
                bfm[nt] = *(const short8*)(ldsW + (wn * 64 + nt * 16 + l15) * 64
                                           + (((ks * 4 + quad) ^ swz) * 8));
#pragma unroll
            for (int mt = 0; mt < 2; ++mt)
#pragma unroll
                for (int nt = 0; nt < 4; ++nt)
                    acc[mt][nt] = __builtin_amdgcn_mfma_f32_16x16x32_bf16(
                        af[mt], bfm[nt], acc[mt][nt], 0, 0, 0);
        }
    }

    float biasr[4];
#pragma unroll
    for (int nt = 0; nt < 4; nt++)
        biasr[nt] = bias[colBase + wn * 64 + nt * 16 + l15];

#pragma unroll
    for (int mt = 0; mt < 2; mt++)
#pragma unroll
        for (int reg = 0; reg < 4; reg++) {
            int row = rowBase + wm * 32 + mt * 16 + quad * 4 + reg;
            float* dst = OF + (size_t)row * ND + colBase + wn * 64 + l15;
#pragma unroll
            for (int nt = 0; nt < 4; nt++)
                dst[nt * 16] = acc[mt][nt][reg] + biasr[nt];
        }
}

// ---------------------------------------------------------------------------
// Flash attention v9 — 32 q-rows per wave (K/V LDS fragments shared across
// the two 16-row q-tiles -> LDS read bytes per work halved).
// grid (32,8,4)=1024 blocks, 128 thr (2 waves) -> 4 blocks/CU, 8 waves/CU.
// XOR-swizzled chunk layout; DMA staging contiguous (zero write conflicts);
// S^T trick keeps P in registers.
// ---------------------------------------------------------------------------
__global__ __launch_bounds__(128, 2) void attn_kernel(
        const unsigned short* __restrict__ Qb, const unsigned short* __restrict__ Kb,
        const unsigned short* __restrict__ VTb, unsigned short* __restrict__ Cb) {
    const int qt = blockIdx.x, h = blockIdx.y, b = blockIdx.z;
    __shared__ alignas(16) unsigned short Ks[64 * 64];   // 8 KB
    __shared__ alignas(16) unsigned short Vt[64 * 64];   // 8 KB

    const int tid = threadIdx.x, lane = tid & 63, wave = tid >> 6;  // wave 0..1
    const int quad = lane >> 4, l15 = lane & 15;
    const size_t headOff = (size_t)h * NDK;
    const size_t rowB = (size_t)b * NT;
    const unsigned short* VT = VTb + (size_t)(b * NH + h) * ((size_t)NDK * NT);

    // Q fragments: wave covers q-rows [wave*32, wave*32+32), mt splits 16+16
    short8 aq[2][2];
#pragma unroll
    for (int mt = 0; mt < 2; ++mt)
#pragma unroll
        for (int ks = 0; ks < 2; ++ks)
            aq[mt][ks] = *(const short8*)(Qb + (rowB + qt * 64 + wave * 32 + mt * 16 + l15) * ND
                                          + headOff + ks * 32 + quad * 8);

    // staging: call c covers rows c*16 + (tid>>3); chunk g=(tid&7)^((tid>>3)&7)
    const int rS = tid >> 3;                      // 0..15
    const int gcs = (tid & 7) ^ (rS & 7);         // call-invariant
    const unsigned short* gK = Kb + rowB * ND + headOff + (size_t)rS * ND + gcs * 8;
    const unsigned short* gV = VT + (size_t)rS * NT + gcs * 8;
    const int ldst = wave * 512;                  // + c*1024

    // hoisted LDS read bases (shared across mt)
    const int swz = l15 & 7;
    const int qh = quad >> 1, qlo = quad & 1;
    const unsigned short* kb0 = Ks + l15 * 64 + ((quad ^ swz) * 8);
    const unsigned short* kb1 = Ks + l15 * 64 + (((4 + quad) ^ swz) * 8);
    const unsigned short* vbp[4];
#pragma unroll
    for (int kt = 0; kt < 4; ++kt)
        vbp[kt] = Vt + l15 * 64 + (((kt * 2 + qh) ^ swz) * 8) + qlo * 4;

    f32x4 o[2][4];
#pragma unroll
    for (int mt = 0; mt < 2; mt++)
#pragma unroll
        for (int nt = 0; nt < 4; nt++) o[mt][nt] = (f32x4)0.0f;
    float lacc[2] = {0.f, 0.f};

    for (int kv = 0; kv < NT / 64; ++kv) {
        __syncthreads();                  // prior iter done reading Ks/Vt
#pragma unroll
        for (int c = 0; c < 4; ++c) {
            load_lds16(gK + (size_t)c * 16 * ND, Ks + c * 1024 + ldst);
            load_lds16(gV + (size_t)c * 16 * NT, Vt + c * 1024 + ldst);
        }
        gK += 64 * ND; gV += 64;
        __syncthreads();                  // vmcnt(0) drained -> tiles visible

        // S^T tiles + softmax -> packed bf16 P fragments (registers only)
        bs4 pk[4][2];
#pragma unroll
        for (int kt = 0; kt < 4; ++kt) {
            short8 ak0 = *(const short8*)(kb0 + kt * 1024);
            short8 ak1 = *(const short8*)(kb1 + kt * 1024);
#pragma unroll
            for (int mt = 0; mt < 2; ++mt) {
                f32x4 st = (f32x4)0.0f;
                st = __builtin_amdgcn_mfma_f32_16x16x32_bf16(ak0, aq[mt][0], st, 0, 0, 0);
                st = __builtin_amdgcn_mfma_f32_16x16x32_bf16(ak1, aq[mt][1], st, 0, 0, 0);
                float p0 = exp2f(st[0]), p1 = exp2f(st[1]);
                float p2 = exp2f(st[2]), p3 = exp2f(st[3]);
                lacc[mt] += (p0 + p1) + (p2 + p3);
                uint32_t lo = __builtin_amdgcn_perm(__float_as_uint(p1), __float_as_uint(p0),
                                                    0x07060302u);
                uint32_t hi = __builtin_amdgcn_perm(__float_as_uint(p3), __float_as_uint(p2),
                                                    0x07060302u);
                union { uint32_t w[2]; bs4 v; } cvt;
                cvt.w[0] = lo; cvt.w[1] = hi;
                pk[kt][mt] = cvt.v;
            }
        }

        // O += P V  (V fragments shared across mt)
#pragma unroll
        for (int kt = 0; kt < 4; ++kt)
#pragma unroll
            for (int nt = 0; nt < 4; ++nt) {
                bs4 vbf = *(const bs4*)(vbp[kt] + nt * 1024);
                o[0][nt] = __builtin_amdgcn_mfma_f32_16x16x16bf16_1k(pk[kt][0], vbf, o[0][nt], 0, 0, 0);
                o[1][nt] = __builtin_amdgcn_mfma_f32_16x16x16bf16_1k(pk[kt][1], vbf, o[1][nt], 0, 0, 0);
            }
    }

    // denominators + write
#pragma unroll
    for (int mt = 0; mt < 2; ++mt) {
        float l = lacc[mt];
        l += __shfl_xor(l, 16);
        l += __shfl_xor(l, 32);
#pragma unroll
        for (int reg = 0; reg < 4; ++reg) {
            float inv = 1.0f / __shfl(l, quad * 4 + reg);
            size_t row = rowB + qt * 64 + wave * 32 + mt * 16 + quad * 4 + reg;
#pragma unroll
            for (int nt = 0; nt < 4; ++nt)
                Cb[row * ND + headOff + nt * 16 + l15] = f2b(o[mt][nt][reg] * inv);
        }
    }
}

// ---------------------------------------------------------------------------
extern "C" void kernel_launch(void* const* d_in, const int* in_sizes, int n_in,
                              void* d_out, int out_size, void* d_ws, size_t ws_size,
                              hipStream_t stream) {
    (void)in_sizes; (void)n_in; (void)out_size; (void)ws_size;
    const float* x  = (const float*)d_in[0];
    const float* Wq = (const float*)d_in[1];
    const float* bq = (const float*)d_in[2];
    const float* Wk = (const float*)d_in[3];
    const float* bk = (const float*)d_in[4];
    const float* Wv = (const float*)d_in[5];
    const float* bv = (const float*)d_in[6];
    const float* Wo = (const float*)d_in[7];
    const float* bo = (const float*)d_in[8];
    float* out = (float*)d_out;

    unsigned short* ws  = (unsigned short*)d_ws;
    unsigned short* xb  = ws;                   // 4194304 elems
    unsigned short* wqb = xb + 4194304;         // 4 x 262144 (wq,wk,wv,wo)
    unsigned short* Qb  = wqb + 4 * 262144;     // Q,K,VT,C 4194304 each
    unsigned short* Kb  = Qb + 4194304;
    unsigned short* VTb = Kb + 4194304;
    unsigned short* Cb  = VTb + 4194304;
    unsigned short* wob = wqb + 3 * 262144;

    convert_all<<<5120, 256, 0, stream>>>(x, Wq, Wk, Wv, Wo, ws);

    // fold 1/sqrt(dk) * log2(e) into Q so softmax uses exp2
    const float qscale = 0.125f * 1.44269504f;
    proj_gemm<<<dim3(4, 64, 3), 256, 0, stream>>>(xb, wqb, bq, bk, bv, Qb, VTb, qscale);
    attn_kernel<<<dim3(32, 8, 4), 128, 0, stream>>>(Qb, Kb, VTb, Cb);
    out_gemm<<<dim3(4, 128), 256, 0, stream>>>(Cb, wob, bo, out);
}

// Round 11
// 177.372 us; speedup vs baseline: 1.0645x; 1.0645x over previous
//
#include <hip/hip_runtime.h>
#include <stdint.h>

#define NB 4
#define NT 2048
#define ND 512
#define NH 8
#define NDK 64
#define NM (NB*NT)   // 8192 rows

typedef __attribute__((ext_vector_type(8))) short short8;
typedef __attribute__((ext_vector_type(4))) short bs4;     // 4 bf16 (2 VGPR)
typedef __attribute__((ext_vector_type(4))) float f32x4;

// round-to-nearest-even fp32 -> bf16
__device__ __forceinline__ unsigned short f2b(float f) {
    union { float f; uint32_t u; } v; v.f = f;
    return (unsigned short)((v.u + 0x7FFFu + ((v.u >> 16) & 1u)) >> 16);
}

__device__ __forceinline__ void load_lds16(const void* g, void* l) {
    void* gn = const_cast<void*>(g);
    __builtin_amdgcn_global_load_lds((__attribute__((address_space(1))) void*)gn,
                                     (__attribute__((address_space(3))) void*)l,
                                     16, 0, 0);
}

// ---------------------------------------------------------------------------
// fp32 -> bf16 conversion of x + Wq,Wk,Wv,Wo, packed into ws.
// ---------------------------------------------------------------------------
__global__ void convert_all(const float* __restrict__ x,  const float* __restrict__ wq,
                            const float* __restrict__ wk, const float* __restrict__ wv,
                            const float* __restrict__ wo, unsigned short* __restrict__ dst) {
    size_t i = ((size_t)blockIdx.x * 256 + threadIdx.x) * 4;
    const float* src; size_t off;
    if (i < 4194304) { src = x; off = i; }
    else {
        size_t j = i - 4194304;
        src = (j < 262144) ? wq : (j < 524288) ? wk : (j < 786432) ? wv : wo;
        off = j & 262143;
    }
    f32x4 v = *(const f32x4*)(src + off);
    ushort4 r;
    r.x = f2b(v[0]); r.y = f2b(v[1]); r.z = f2b(v[2]); r.w = f2b(v[3]);
    *(ushort4*)(dst + i) = r;
}

// ---------------------------------------------------------------------------
// Projections. z=0: Q = x@Wq.T (scaled), z=1: K = x@Wk.T  -> row-major bf16.
// z=2: VT = Wv@x.T directly -> VT[(b*8+h)*64+d][t], coalesced along t.
// BK=64, XOR-swizzled chunks (round-10 WIN: -12.5 us vs BK=32 unswizzled).
// ---------------------------------------------------------------------------
__global__ __launch_bounds__(256, 3) void proj_gemm(
        const unsigned short* __restrict__ X,
        const unsigned short* __restrict__ Wbase,
        const float* __restrict__ bias0, const float* __restrict__ bias1,
        const float* __restrict__ bias2,
        unsigned short* __restrict__ Obase, unsigned short* __restrict__ VTb,
        float scale0) {
    const int z = blockIdx.z;
    const float* bias = (z == 0) ? bias0 : (z == 1 ? bias1 : bias2);
    const float scale = (z == 0) ? scale0 : 1.0f;

    int rowBase, colBase;
    const unsigned short *Ap, *Bp;
    if (z == 2) {   // A = Wv (rows=d), B = x (rows=t)
        rowBase = blockIdx.x * 128;  colBase = blockIdx.y * 128;
        Ap = Wbase + 2 * (ND * ND);  Bp = X;
    } else {        // A = x (rows=t), B = Wq/Wk (rows=d)
        rowBase = blockIdx.y * 128;  colBase = blockIdx.x * 128;
        Ap = X;                      Bp = Wbase + (size_t)z * (ND * ND);
    }

    __shared__ alignas(16) unsigned short ldsA[128 * 64];   // 16 KB
    __shared__ alignas(16) unsigned short ldsW[128 * 64];   // 16 KB

    const int tid = threadIdx.x;
    const int lane = tid & 63, wave = tid >> 6;
    const int quad = lane >> 4, l15 = lane & 15;
    const int wm = wave >> 1, wn = wave & 1;

    const int rS = tid >> 3;                      // 0..31
    const int gc = (tid & 7) ^ (rS & 7);          // call-invariant
    const unsigned short* gA = Ap + (size_t)(rowBase + rS) * ND + gc * 8;
    const unsigned short* gW = Bp + (size_t)(colBase + rS) * ND + gc * 8;
    const int ldst = wave * 512;                  // + c*2048

    const int swz = l15 & 7;

    f32x4 acc[4][4];
#pragma unroll
    for (int i = 0; i < 4; i++)
#pragma unroll
        for (int j = 0; j < 4; j++) acc[i][j] = (f32x4)0.0f;

    for (int kt = 0; kt < ND / 64; ++kt) {
        __syncthreads();
#pragma unroll
        for (int c = 0; c < 4; ++c) {
            load_lds16(gA + (size_t)c * 32 * ND, ldsA + c * 2048 + ldst);
            load_lds16(gW + (size_t)c * 32 * ND, ldsW + c * 2048 + ldst);
        }
        gA += 64; gW += 64;
        __syncthreads();

#pragma unroll
        for (int ks = 0; ks < 2; ++ks) {
            short8 af[4], bfm[4];
#pragma unroll
            for (int mt = 0; mt < 4; ++mt)
                af[mt] = *(const short8*)(ldsA + (wm * 64 + mt * 16 + l15) * 64
                                          + (((ks * 4 + quad) ^ swz) * 8));
#pragma unroll
            for (int nt = 0; nt < 4; ++nt)
                bfm[nt] = *(const short8*)(ldsW + (wn * 64 + nt * 16 + l15) * 64
                                           + (((ks * 4 + quad) ^ swz) * 8));
#pragma unroll
            for (int mt = 0; mt < 4; ++mt)
#pragma unroll
                for (int nt = 0; nt < 4; ++nt)
                    acc[mt][nt] = __builtin_amdgcn_mfma_f32_16x16x32_bf16(
                        af[mt], bfm[nt], acc[mt][nt], 0, 0, 0);
        }
    }

    if (z == 2) {
        const int bz = colBase >> 11;
        const int t0 = colBase & 2047;
        unsigned short* VTo = VTb + ((size_t)(bz * 512 + rowBase)) * NT + t0;
#pragma unroll
        for (int mt = 0; mt < 4; mt++)
#pragma unroll
            for (int reg = 0; reg < 4; reg++) {
                int m = wm * 64 + mt * 16 + quad * 4 + reg;
                float bm = bias[rowBase + m];
                unsigned short* dst = VTo + (size_t)m * NT + wn * 64 + l15;
#pragma unroll
                for (int nt = 0; nt < 4; nt++)
                    dst[nt * 16] = f2b(acc[mt][nt][reg] + bm);
            }
    } else {
        float biasr[4];
#pragma unroll
        for (int nt = 0; nt < 4; nt++)
            biasr[nt] = bias[colBase + wn * 64 + nt * 16 + l15];
        unsigned short* Oz = Obase + (size_t)z * ((size_t)NM * ND);
#pragma unroll
        for (int mt = 0; mt < 4; mt++) {
            int row = rowBase + wm * 64 + mt * 16 + quad * 4;
#pragma unroll
            for (int reg = 0; reg < 4; reg++) {
                unsigned short* dst = Oz + (size_t)(row + reg) * ND + colBase + wn * 64 + l15;
#pragma unroll
                for (int nt = 0; nt < 4; nt++)
                    dst[nt * 16] = f2b((acc[mt][nt][reg] + biasr[nt]) * scale);
            }
        }
    }
}

// ---------------------------------------------------------------------------
// Output projection (fp32 out): 64x128 tile, 2x2 wave grid, BK=64 + swizzle.
// ---------------------------------------------------------------------------
__global__ __launch_bounds__(256, 4) void out_gemm(
        const unsigned short* __restrict__ A, const unsigned short* __restrict__ W,
        const float* __restrict__ bias, float* __restrict__ OF) {
    __shared__ alignas(16) unsigned short ldsA[64 * 64];    // 8 KB
    __shared__ alignas(16) unsigned short ldsW[128 * 64];   // 16 KB

    const int tid = threadIdx.x;
    const int lane = tid & 63, wave = tid >> 6;
    const int quad = lane >> 4, l15 = lane & 15;
    const int wm = wave >> 1, wn = wave & 1;
    const int rowBase = blockIdx.y * 64;
    const int colBase = blockIdx.x * 128;

    const int rS = tid >> 3;
    const int gc = (tid & 7) ^ (rS & 7);
    const unsigned short* gA = A + (size_t)(rowBase + rS) * ND + gc * 8;
    const unsigned short* gW = W + (size_t)(colBase + rS) * ND + gc * 8;
    const int ldst = wave * 512;
    const int swz = l15 & 7;

    f32x4 acc[2][4];
#pragma unroll
    for (int mt = 0; mt < 2; mt++)
#pragma unroll
        for (int nt = 0; nt < 4; nt++) acc[mt][nt] = (f32x4)0.0f;

    for (int kt = 0; kt < ND / 64; ++kt) {
        __syncthreads();
#pragma unroll
        for (int c = 0; c < 2; ++c)
            load_lds16(gA + (size_t)c * 32 * ND, ldsA + c * 2048 + ldst);
#pragma unroll
        for (int c = 0; c < 4; ++c)
            load_lds16(gW + (size_t)c * 32 * ND, ldsW + c * 2048 + ldst);
        gA += 64; gW += 64;
        __syncthreads();

#pragma unroll
        for (int ks = 0; ks < 2; ++ks) {
            short8 af[2], bfm[4];
#pragma unroll
            for (int mt = 0; mt < 2; ++mt)
                af[mt] = *(const short8*)(ldsA + (wm * 32 + mt * 16 + l15) * 64
                                          + (((ks * 4 + quad) ^ swz) * 8));
#pragma unroll
            for (int nt = 0; nt < 4; ++nt)
                bfm[nt] = *(const short8*)(ldsW + (wn * 64 + nt * 16 + l15) * 64
                                           + (((ks * 4 + quad) ^ swz) * 8));
#pragma unroll
            for (int mt = 0; mt < 2; ++mt)
#pragma unroll
                for (int nt = 0; nt < 4; ++nt)
                    acc[mt][nt] = __builtin_amdgcn_mfma_f32_16x16x32_bf16(
                        af[mt], bfm[nt], acc[mt][nt], 0, 0, 0);
        }
    }

    float biasr[4];
#pragma unroll
    for (int nt = 0; nt < 4; nt++)
        biasr[nt] = bias[colBase + wn * 64 + nt * 16 + l15];

#pragma unroll
    for (int mt = 0; mt < 2; mt++)
#pragma unroll
        for (int reg = 0; reg < 4; reg++) {
            int row = rowBase + wm * 32 + mt * 16 + quad * 4 + reg;
            float* dst = OF + (size_t)row * ND + colBase + wn * 64 + l15;
#pragma unroll
            for (int nt = 0; nt < 4; nt++)
                dst[nt * 16] = acc[mt][nt][reg] + biasr[nt];
        }
}

// ---------------------------------------------------------------------------
// Flash attention v10 — v8 wave layout (256 thr, 16 q/wave, 1024 blocks,
// 16 waves/CU) + kv-128 rounds: 2x KV tile per barrier -> half the
// barrier/drain rounds (the BK=64 GEMM win applied to attention).
// LDS: Ks[128x64] + Vt[64x128] = 32 KB (still 4 blocks/CU, grid-limited).
// XOR-swizzled chunks; DMA staging contiguous (zero write conflicts);
// S^T trick keeps P in registers. kt spans 0..7; bit 3 of the chunk index
// passes through the 3-bit XOR, so kt>=4 reads are imm offsets (+128 B).
// ---------------------------------------------------------------------------
__global__ __launch_bounds__(256, 4) void attn_kernel(
        const unsigned short* __restrict__ Qb, const unsigned short* __restrict__ Kb,
        const unsigned short* __restrict__ VTb, unsigned short* __restrict__ Cb) {
    const int qt = blockIdx.x, h = blockIdx.y, b = blockIdx.z;
    __shared__ alignas(16) unsigned short Ks[128 * 64];   // 16 KB, [t'][d]
    __shared__ alignas(16) unsigned short Vt[64 * 128];   // 16 KB, [d][t']

    const int tid = threadIdx.x, lane = tid & 63, wave = tid >> 6;
    const int quad = lane >> 4, l15 = lane & 15;
    const size_t headOff = (size_t)h * NDK;
    const size_t rowB = (size_t)b * NT;
    const unsigned short* VT = VTb + (size_t)(b * NH + h) * ((size_t)NDK * NT);

    // Q fragments (B-operand of S^T MFMA): lane holds Q[q=l15][k=quad*8+j]
    short8 aq[2];
#pragma unroll
    for (int ks = 0; ks < 2; ++ks)
        aq[ks] = *(const short8*)(Qb + (rowB + qt * 64 + wave * 16 + l15) * ND
                                  + headOff + ks * 32 + quad * 8);

    // K staging: call c covers rows c*32+(tid>>3); chunk g=(tid&7)^((tid>>3)&7)
    const int rK = tid >> 3;                      // 0..31
    const int gK8 = (tid & 7) ^ (rK & 7);
    const unsigned short* gK = Kb + (rowB + rK) * ND + headOff + gK8 * 8;
    // V staging: call c covers d-rows c*16+(tid>>4); 16 chunks/row,
    // g = (tid&15) ^ ((tid>>4)&7)  (3-bit XOR preserves bit 3)
    const int rV = tid >> 4;                      // 0..15
    const int gV8 = (tid & 15) ^ (rV & 7);
    const unsigned short* gV = VT + (size_t)rV * NT + gV8 * 8;
    const int ldst = wave * 512;                  // dest: + c*2048 + ldst

    // hoisted LDS read bases
    const int swz = l15 & 7;
    const int qh = quad >> 1, qlo = quad & 1;
    const unsigned short* kb0 = Ks + l15 * 64 + ((quad ^ swz) * 8);
    const unsigned short* kb1 = Ks + l15 * 64 + (((4 + quad) ^ swz) * 8);
    const unsigned short* vbp[4];
#pragma unroll
    for (int k2 = 0; k2 < 4; ++k2)
        vbp[k2] = Vt + l15 * 128 + (((k2 * 2 + qh) ^ swz) * 8) + qlo * 4;

    f32x4 o[4];
#pragma unroll
    for (int nt = 0; nt < 4; nt++) o[nt] = (f32x4)0.0f;
    float lacc = 0.0f;

    for (int kv = 0; kv < NT / 128; ++kv) {       // 16 rounds
        __syncthreads();                  // prior round done reading Ks/Vt
#pragma unroll
        for (int c = 0; c < 4; ++c) {
            load_lds16(gK + (size_t)c * 32 * ND, Ks + c * 2048 + ldst);
            load_lds16(gV + (size_t)c * 16 * NT, Vt + c * 2048 + ldst);
        }
        gK += 128 * ND; gV += 128;
        __syncthreads();                  // vmcnt(0) drained -> tiles visible

        // 8 key-tiles: S^T + softmax + PV per tile (P never leaves registers)
#pragma unroll
        for (int kt = 0; kt < 8; ++kt) {
            f32x4 st = (f32x4)0.0f;
            st = __builtin_amdgcn_mfma_f32_16x16x32_bf16(
                *(const short8*)(kb0 + kt * 1024), aq[0], st, 0, 0, 0);
            st = __builtin_amdgcn_mfma_f32_16x16x32_bf16(
                *(const short8*)(kb1 + kt * 1024), aq[1], st, 0, 0, 0);
            float p0 = exp2f(st[0]), p1 = exp2f(st[1]);
            float p2 = exp2f(st[2]), p3 = exp2f(st[3]);
            lacc += (p0 + p1) + (p2 + p3);
            uint32_t lo = __builtin_amdgcn_perm(__float_as_uint(p1), __float_as_uint(p0),
                                                0x07060302u);
            uint32_t hi = __builtin_amdgcn_perm(__float_as_uint(p3), __float_as_uint(p2),
                                                0x07060302u);
            union { uint32_t w[2]; bs4 v; } cvt;
            cvt.w[0] = lo; cvt.w[1] = hi;
            const unsigned short* vb = vbp[kt & 3] + (kt >> 2) * 64;
#pragma unroll
            for (int nt = 0; nt < 4; ++nt)
                o[nt] = __builtin_amdgcn_mfma_f32_16x16x16bf16_1k(
                    cvt.v, *(const bs4*)(vb + nt * 2048), o[nt], 0, 0, 0);
        }
    }

    // denominator: fold quads -> every lane holds full sum for q-row l15
    lacc += __shfl_xor(lacc, 16);
    lacc += __shfl_xor(lacc, 32);

#pragma unroll
    for (int reg = 0; reg < 4; ++reg) {
        float inv = 1.0f / __shfl(lacc, quad * 4 + reg);
        size_t row = rowB + qt * 64 + wave * 16 + quad * 4 + reg;
#pragma unroll
        for (int nt = 0; nt < 4; ++nt)
            Cb[row * ND + headOff + nt * 16 + l15] = f2b(o[nt][reg] * inv);
    }
}

// ---------------------------------------------------------------------------
extern "C" void kernel_launch(void* const* d_in, const int* in_sizes, int n_in,
                              void* d_out, int out_size, void* d_ws, size_t ws_size,
                              hipStream_t stream) {
    (void)in_sizes; (void)n_in; (void)out_size; (void)ws_size;
    const float* x  = (const float*)d_in[0];
    const float* Wq = (const float*)d_in[1];
    const float* bq = (const float*)d_in[2];
    const float* Wk = (const float*)d_in[3];
    const float* bk = (const float*)d_in[4];
    const float* Wv = (const float*)d_in[5];
    const float* bv = (const float*)d_in[6];
    const float* Wo = (const float*)d_in[7];
    const float* bo = (const float*)d_in[8];
    float* out = (float*)d_out;

    unsigned short* ws  = (unsigned short*)d_ws;
    unsigned short* xb  = ws;                   // 4194304 elems
    unsigned short* wqb = xb + 4194304;         // 4 x 262144 (wq,wk,wv,wo)
    unsigned short* Qb  = wqb + 4 * 262144;     // Q,K,VT,C 4194304 each
    unsigned short* Kb  = Qb + 4194304;
    unsigned short* VTb = Kb + 4194304;
    unsigned short* Cb  = VTb + 4194304;
    unsigned short* wob = wqb + 3 * 262144;

    convert_all<<<5120, 256, 0, stream>>>(x, Wq, Wk, Wv, Wo, ws);

    // fold 1/sqrt(dk) * log2(e) into Q so softmax uses exp2
    const float qscale = 0.125f * 1.44269504f;
    proj_gemm<<<dim3(4, 64, 3), 256, 0, stream>>>(xb, wqb, bq, bk, bv, Qb, VTb, qscale);
    attn_kernel<<<dim3(32, 8, 4), 256, 0, stream>>>(Qb, Kb, VTb, Cb);
    out_gemm<<<dim3(4, 128), 256, 0, stream>>>(Cb, wob, bo, out);
}